// Round 5
// baseline (213.440 us; speedup 1.0000x reference)
//
#include <hip/hip_runtime.h>
#include <math.h>

#define N_NODES 50000
#define KNEI    32
#define DIM     128
#define DOUT    128
#define NSLICE_ELEMS (N_NODES * 32)    // elements per 32-col slice of Gs

typedef __attribute__((ext_vector_type(8))) short short8;
typedef __attribute__((ext_vector_type(4))) float floatx4;

// round-to-nearest-even fp32 -> bf16
static __device__ __forceinline__ unsigned short f2bf(float f) {
    unsigned int u = __float_as_uint(f);
    unsigned int lsb = (u >> 16) & 1u;
    u += 0x7fffu + lsb;
    return (unsigned short)(u >> 16);
}
static __device__ __forceinline__ unsigned int pack2(float a, float b) {
    return (unsigned int)f2bf(a) | ((unsigned int)f2bf(b) << 16);
}

// ---------------- fast path kernels ----------------

// fea1 fp32 [N,128] -> slice-major bf16 gather table Gs[4][N][32]
__global__ __launch_bounds__(256) void convert_gs(
    const float* __restrict__ src, unsigned short* __restrict__ Gs)
{
    int t = blockIdx.x * 256 + threadIdx.x;   // 0 .. N*16-1
    int n = t >> 4;
    int q = t & 15;
    int s = q >> 2;        // slice 0..3
    int p = q & 3;         // 8-col part within slice
    const float* rp = src + n * DIM + s * 32 + p * 8;
    float4 v0 = *(const float4*)rp;
    float4 v1 = *(const float4*)(rp + 4);
    int4 o;
    o.x = (int)pack2(v0.x, v0.y);
    o.y = (int)pack2(v0.z, v0.w);
    o.z = (int)pack2(v1.x, v1.y);
    o.w = (int)pack2(v1.z, v1.w);
    *(int4*)(Gs + (size_t)s * NSLICE_ELEMS + n * 32 + p * 8) = o;
}

// W fp32 [512,128] -> Wt bf16 [128][512]
__global__ __launch_bounds__(256) void transpose_w(
    const float* __restrict__ W, unsigned short* __restrict__ Wt)
{
    int t = blockIdx.x * 256 + threadIdx.x;   // 0..65535
    int k = t >> 7, n = t & 127;
    Wt[n * 512 + k] = f2bf(W[t]);
}

// slice-phased gather-mean.  grid = 4 slices x 6250 blocks (slice outermost),
// 1024 thr = 16 wave-units per block, one wave per (node,list).
__global__ __launch_bounds__(1024) void aggregate_s(
    const unsigned short* __restrict__ Gs,
    const int* __restrict__ idx1,
    const int* __restrict__ idx2,
    unsigned short* __restrict__ NEI)
{
    const int bx   = blockIdx.x;
    const int s    = bx / 6250;                 // slice (outer in dispatch order)
    const int r    = bx - s * 6250;
    const int tid  = threadIdx.x;
    const int u    = r * 16 + (tid >> 6);       // wave-unit 0..99999
    const int node = u >> 1;
    const int list = u & 1;
    const int lane = tid & 63;
    const int grp  = lane >> 4;                 // 0..3: which row of each 4-row batch
    const int li   = lane & 15;                 // 2-col position within the 32-col slice

    const int* ip = (list ? idx2 : idx1) + node * KNEI;
    int nb = ip[lane & 31];                     // row index held by lanes 0..31

    const unsigned short* base = Gs + (size_t)s * NSLICE_ELEMS;
    float s0 = 0.f, s1 = 0.f;
    #pragma unroll
    for (int b = 0; b < 8; ++b) {
        int rq = __shfl(nb, b * 4 + grp, 64);
        unsigned int v = *(const unsigned int*)(base + rq * 32 + li * 2);
        s0 += __uint_as_float(v << 16);
        s1 += __uint_as_float(v & 0xffff0000u);
    }
    // butterfly-reduce the 4 lane-groups (each summed 8 of the 32 rows)
    s0 += __shfl_xor(s0, 16, 64);
    s1 += __shfl_xor(s1, 16, 64);
    s0 += __shfl_xor(s0, 32, 64);
    s1 += __shfl_xor(s1, 32, 64);

    if (lane < 16) {
        unsigned int o = pack2(s0 * (1.f / 32.f), s1 * (1.f / 32.f));
        *(unsigned int*)(NEI + node * 256 + list * 128 + s * 32 + li * 2) = o;
    }
}

// out = tanh([fea1|fea2|NEI] @ Wt^T) ; fp32 feas converted to bf16 inline
__global__ __launch_bounds__(256) void gemm_tanh2(
    const float*          __restrict__ fea1,
    const float*          __restrict__ fea2,
    const unsigned short* __restrict__ NEI,
    const unsigned short* __restrict__ Wt,
    float* __restrict__ out)
{
    __shared__ unsigned short As[64][72];    // 9216 B
    __shared__ unsigned short Bs[128][72];   // 18432 B

    const int tid  = threadIdx.x;
    const int w    = tid >> 6;
    const int lane = tid & 63;
    const int m0   = blockIdx.x * 64;
    const int wm   = (w & 1) * 32;
    const int wn   = (w >> 1) * 64;
    const int lm   = lane & 15;
    const int lk   = (lane >> 4) * 8;

    floatx4 acc[2][4];
    #pragma unroll
    for (int i = 0; i < 2; ++i)
        #pragma unroll
        for (int j = 0; j < 4; ++j)
            acc[i][j] = (floatx4){0.f, 0.f, 0.f, 0.f};

    for (int c = 0; c < 8; ++c) {
        const int kb = c * 64;
        if (c < 4) {
            // fp32 direct features, convert inline: 64 rows x 64 cols
            const float* src = (c < 2) ? fea1 : fea2;
            const int cbase = (c & 1) * 64;
            #pragma unroll
            for (int i = 0; i < 4; ++i) {
                int f = tid + i * 256;        // 1024 float4 slots
                int row = f >> 4;             // 16 float4 per 64-col row
                int c4 = (f & 15) * 4;
                int node = m0 + row;
                if (node >= N_NODES) node = N_NODES - 1;
                float4 v = *(const float4*)(src + node * DIM + cbase + c4);
                unsigned int lo = pack2(v.x, v.y);
                unsigned int hi = pack2(v.z, v.w);
                *(unsigned int*)&As[row][c4 + 0] = lo;
                *(unsigned int*)&As[row][c4 + 2] = hi;
            }
        } else {
            // NEI bf16: 64 rows x 64 cols = 512 int4 slots
            const int cb = kb - 256;
            #pragma unroll
            for (int i = 0; i < 2; ++i) {
                int sl = tid + i * 256;
                int row = sl >> 3, o = (sl & 7) * 8;
                int node = m0 + row;
                if (node >= N_NODES) node = N_NODES - 1;
                *(int4*)&As[row][o] = *(const int4*)(NEI + node * 256 + cb + o);
            }
        }
        // B tile: 128 out-cols x 64 k = 1024 int4 slots
        #pragma unroll
        for (int i = 0; i < 4; ++i) {
            int sl = tid + i * 256;
            int row = sl >> 3, o = (sl & 7) * 8;
            *(int4*)&Bs[row][o] = *(const int4*)(Wt + row * 512 + kb + o);
        }
        __syncthreads();

        #pragma unroll
        for (int ks = 0; ks < 64; ks += 32) {
            short8 af[2], bf_[4];
            #pragma unroll
            for (int im = 0; im < 2; ++im)
                af[im] = *(const short8*)&As[wm + im * 16 + lm][ks + lk];
            #pragma unroll
            for (int in = 0; in < 4; ++in)
                bf_[in] = *(const short8*)&Bs[wn + in * 16 + lm][ks + lk];
            #pragma unroll
            for (int im = 0; im < 2; ++im)
                #pragma unroll
                for (int in = 0; in < 4; ++in)
                    acc[im][in] = __builtin_amdgcn_mfma_f32_16x16x32_bf16(
                        af[im], bf_[in], acc[im][in], 0, 0, 0);
        }
        __syncthreads();
    }

    // epilogue (C/D: col=lane&15, row=(lane>>4)*4+reg) — verified in round 4
    #pragma unroll
    for (int im = 0; im < 2; ++im) {
        int rbase = m0 + wm + im * 16 + (lane >> 4) * 4;
        #pragma unroll
        for (int in = 0; in < 4; ++in) {
            int col = wn + in * 16 + lm;
            #pragma unroll
            for (int r = 0; r < 4; ++r) {
                int node = rbase + r;
                if (node < N_NODES)
                    out[node * DOUT + col] = tanhf(acc[im][in][r]);
            }
        }
    }
}

// ---------------- fallback (ws too small): round-1 fused fp32 ----------------
#define MT      64
#define KC      64
#define AS_STRIDE 68

__global__ __launch_bounds__(256) void sage_fused_fb(
    const float* __restrict__ fea1, const float* __restrict__ fea2,
    const int* __restrict__ idx1, const int* __restrict__ idx2,
    const float* __restrict__ W, float* __restrict__ out)
{
    __shared__ float As[KC][AS_STRIDE];
    __shared__ int   idxs[MT][64];
    const int tid = threadIdx.x;
    const int n0  = blockIdx.x * MT;
    #pragma unroll
    for (int i = 0; i < 8; ++i) {
        int e = tid + i * 256, m = e >> 5, kk = e & 31;
        int node = n0 + m; if (node >= N_NODES) node = N_NODES - 1;
        idxs[m][kk]      = idx1[node * KNEI + kk];
        idxs[m][32 + kk] = idx2[node * KNEI + kk];
    }
    float acc[8][4];
    #pragma unroll
    for (int i = 0; i < 8; ++i)
        #pragma unroll
        for (int j = 0; j < 4; ++j) acc[i][j] = 0.f;
    const int j0 = (tid & 31) * 4;
    const int m0 = (tid >> 5) * 8;
    for (int c = 0; c < 8; ++c) {
        if (c < 4) {
            const float* src = (c < 2) ? fea1 : fea2;
            const int cbase = (c & 1) * 64;
            #pragma unroll
            for (int i = 0; i < 4; ++i) {
                int f = tid + i * 256, m = f >> 4, c4 = (f & 15) * 4;
                int node = n0 + m; if (node >= N_NODES) node = N_NODES - 1;
                float4 v = *(const float4*)(src + node * DIM + cbase + c4);
                As[c4 + 0][m] = v.x; As[c4 + 1][m] = v.y;
                As[c4 + 2][m] = v.z; As[c4 + 3][m] = v.w;
            }
        } else {
            const int col = tid & 63, kbase = (c & 1) * 64;
            const int lbase = (c < 6) ? 0 : 32, g = tid >> 6;
            for (int mm = 0; mm < 16; ++mm) {
                const int m = g * 16 + mm;
                const int4* ip = (const int4*)&idxs[m][lbase];
                float s = 0.f;
                #pragma unroll
                for (int q = 0; q < 8; ++q) {
                    int4 nb = ip[q];
                    s += fea1[nb.x * DIM + kbase + col];
                    s += fea1[nb.y * DIM + kbase + col];
                    s += fea1[nb.z * DIM + kbase + col];
                    s += fea1[nb.w * DIM + kbase + col];
                }
                As[col][m] = s * (1.0f / 32.0f);
            }
        }
        __syncthreads();
        const float* wp = W + (c * KC) * DOUT + j0;
        #pragma unroll 4
        for (int k = 0; k < KC; ++k) {
            float4 w4 = *(const float4*)(wp + k * DOUT);
            const float4* ap = (const float4*)&As[k][m0];
            float4 a0 = ap[0]; float4 a1 = ap[1];
            float av[8] = {a0.x, a0.y, a0.z, a0.w, a1.x, a1.y, a1.z, a1.w};
            #pragma unroll
            for (int i = 0; i < 8; ++i) {
                acc[i][0] += av[i] * w4.x; acc[i][1] += av[i] * w4.y;
                acc[i][2] += av[i] * w4.z; acc[i][3] += av[i] * w4.w;
            }
        }
        __syncthreads();
    }
    #pragma unroll
    for (int i = 0; i < 8; ++i) {
        int node = n0 + m0 + i;
        if (node < N_NODES) {
            float4 r;
            r.x = tanhf(acc[i][0]); r.y = tanhf(acc[i][1]);
            r.z = tanhf(acc[i][2]); r.w = tanhf(acc[i][3]);
            *(float4*)(out + node * DOUT + j0) = r;
        }
    }
}

extern "C" void kernel_launch(void* const* d_in, const int* in_sizes, int n_in,
                              void* d_out, int out_size, void* d_ws, size_t ws_size,
                              hipStream_t stream) {
    const float* fea1 = (const float*)d_in[0];
    const float* fea2 = (const float*)d_in[1];
    const int*   idx1 = (const int*)d_in[2];
    const int*   idx2 = (const int*)d_in[3];
    const float* W    = (const float*)d_in[4];
    float* out = (float*)d_out;

    const size_t GS_BYTES  = (size_t)4 * NSLICE_ELEMS * 2;     // 12,800,000
    const size_t NEI_BYTES = (size_t)N_NODES * 256 * 2;        // 25,600,000
    const size_t WT_BYTES  = (size_t)512 * 128 * 2;            // 131,072

    if (ws_size >= GS_BYTES + NEI_BYTES + WT_BYTES) {
        unsigned short* Gs  = (unsigned short*)d_ws;
        unsigned short* NEI = (unsigned short*)((char*)d_ws + GS_BYTES);
        unsigned short* Wt  = (unsigned short*)((char*)d_ws + GS_BYTES + NEI_BYTES);

        convert_gs<<<N_NODES * 16 / 256, 256, 0, stream>>>(fea1, Gs);
        transpose_w<<<512 * 128 / 256, 256, 0, stream>>>(W, Wt);
        aggregate_s<<<4 * 6250, 1024, 0, stream>>>(Gs, idx1, idx2, NEI);
        gemm_tanh2<<<(N_NODES + 63) / 64, 256, 0, stream>>>(fea1, fea2, NEI, Wt, out);
    } else {
        const int grid = (N_NODES + MT - 1) / MT;
        sage_fused_fb<<<grid, 256, 0, stream>>>(fea1, fea2, idx1, idx2, W, out);
    }
}

// Round 6
// 195.465 us; speedup vs baseline: 1.0920x; 1.0920x over previous
//
#include <hip/hip_runtime.h>
#include <math.h>

#define N_NODES 50000
#define KNEI    32
#define DIM     128
#define DOUT    128
#define NSLICE_ELEMS (N_NODES * 32)    // elements per 32-col slice of Gs
#define NUNITS  (2 * N_NODES)          // (node,list) units
#define UPB     64                     // units per 256-thread block (4 lanes/unit)
#define NBLK    ((NUNITS + UPB - 1) / UPB)   // 1563 blocks per slice

typedef __attribute__((ext_vector_type(8))) short short8;
typedef __attribute__((ext_vector_type(4))) float floatx4;

// round-to-nearest-even fp32 -> bf16
static __device__ __forceinline__ unsigned short f2bf(float f) {
    unsigned int u = __float_as_uint(f);
    unsigned int lsb = (u >> 16) & 1u;
    u += 0x7fffu + lsb;
    return (unsigned short)(u >> 16);
}
static __device__ __forceinline__ unsigned int pack2(float a, float b) {
    return (unsigned int)f2bf(a) | ((unsigned int)f2bf(b) << 16);
}
// overflow-safe fast tanh: 1 - 2/(e^{2|x|}+1), sign-restored
static __device__ __forceinline__ float fast_tanh(float x) {
    float ax = fabsf(x);
    float e  = __expf(2.0f * ax);
    float t  = 1.0f - 2.0f / (e + 1.0f);
    return copysignf(t, x);
}

// ---------------- fast path kernels ----------------

// fea1 fp32 -> slice-major bf16 Gs[4][N][32]; fea2 fp32 -> row-major bf16 F2[N][128]
__global__ __launch_bounds__(256) void convert2(
    const float* __restrict__ fea1, const float* __restrict__ fea2,
    unsigned short* __restrict__ Gs, unsigned short* __restrict__ F2)
{
    int t = blockIdx.x * 256 + threadIdx.x;   // 0 .. 2*N*16-1
    if (t < N_NODES * 16) {
        int n = t >> 4, q = t & 15;
        int s = q >> 2, p = q & 3;
        const float* rp = fea1 + n * DIM + s * 32 + p * 8;
        float4 v0 = *(const float4*)rp;
        float4 v1 = *(const float4*)(rp + 4);
        int4 o;
        o.x = (int)pack2(v0.x, v0.y);
        o.y = (int)pack2(v0.z, v0.w);
        o.z = (int)pack2(v1.x, v1.y);
        o.w = (int)pack2(v1.z, v1.w);
        *(int4*)(Gs + (size_t)s * NSLICE_ELEMS + n * 32 + p * 8) = o;
    } else {
        t -= N_NODES * 16;
        int n = t >> 4, q = t & 15;
        const float* rp = fea2 + n * DIM + q * 8;
        float4 v0 = *(const float4*)rp;
        float4 v1 = *(const float4*)(rp + 4);
        int4 o;
        o.x = (int)pack2(v0.x, v0.y);
        o.y = (int)pack2(v0.z, v0.w);
        o.z = (int)pack2(v1.x, v1.y);
        o.w = (int)pack2(v1.z, v1.w);
        *(int4*)(F2 + n * DIM + q * 8) = o;
    }
}

// W fp32 [512,128] -> Wt bf16 [128][512]
__global__ __launch_bounds__(256) void transpose_w(
    const float* __restrict__ W, unsigned short* __restrict__ Wt)
{
    int t = blockIdx.x * 256 + threadIdx.x;   // 0..65535
    int k = t >> 7, n = t & 127;
    Wt[n * 512 + k] = f2bf(W[t]);
}

// slice-phased gather-mean, 16 units/wave, 4 lanes/unit, int4 loads, no shuffles.
// grid = 4 * NBLK (slice outermost for per-XCD L2 phasing)
__global__ __launch_bounds__(256, 4) void aggregate3(
    const unsigned short* __restrict__ Gs,
    const int* __restrict__ idx1,
    const int* __restrict__ idx2,
    unsigned short* __restrict__ NEI)
{
    const int bx  = blockIdx.x;
    const int s   = bx / NBLK;
    const int r   = bx - s * NBLK;
    const int tid = threadIdx.x;
    int u = r * UPB + (tid >> 2);
    const bool valid = (u < NUNITS);
    if (!valid) u = NUNITS - 1;
    const int node = u >> 1;
    const int list = u & 1;
    const int c    = tid & 3;              // col-chunk: cols c*8 .. c*8+7 of slice s

    // preload all 32 neighbor indices (quad-shared addresses, L1 broadcast)
    const int* ip = (list ? idx2 : idx1) + node * KNEI;
    int4 I[8];
    #pragma unroll
    for (int q = 0; q < 8; ++q) I[q] = *(const int4*)(ip + q * 4);

    const unsigned short* base = Gs + (size_t)s * NSLICE_ELEMS + c * 8;
    float sums[8] = {0.f, 0.f, 0.f, 0.f, 0.f, 0.f, 0.f, 0.f};

    #pragma unroll
    for (int q = 0; q < 8; ++q) {
        int rows[4] = {I[q].x, I[q].y, I[q].z, I[q].w};
        #pragma unroll
        for (int t4 = 0; t4 < 4; ++t4) {
            int4 v = *(const int4*)(base + rows[t4] * 32);
            unsigned int d0 = (unsigned int)v.x, d1 = (unsigned int)v.y;
            unsigned int d2 = (unsigned int)v.z, d3 = (unsigned int)v.w;
            sums[0] += __uint_as_float(d0 << 16);
            sums[1] += __uint_as_float(d0 & 0xffff0000u);
            sums[2] += __uint_as_float(d1 << 16);
            sums[3] += __uint_as_float(d1 & 0xffff0000u);
            sums[4] += __uint_as_float(d2 << 16);
            sums[5] += __uint_as_float(d2 & 0xffff0000u);
            sums[6] += __uint_as_float(d3 << 16);
            sums[7] += __uint_as_float(d3 & 0xffff0000u);
        }
    }

    if (valid) {
        const float inv = 1.0f / 32.0f;
        int4 o;
        o.x = (int)pack2(sums[0] * inv, sums[1] * inv);
        o.y = (int)pack2(sums[2] * inv, sums[3] * inv);
        o.z = (int)pack2(sums[4] * inv, sums[5] * inv);
        o.w = (int)pack2(sums[6] * inv, sums[7] * inv);
        *(int4*)(NEI + node * 256 + list * 128 + s * 32 + c * 8) = o;
    }
}

// out = tanh([fea1|fea2|nei1|nei2] @ Wt^T); 128x128 tile, bf16 MFMA, fp32 accum
__global__ __launch_bounds__(256) void gemm128(
    const unsigned short* __restrict__ Gs,    // fea1 bf16, slice-major
    const unsigned short* __restrict__ F2,    // fea2 bf16, row-major
    const unsigned short* __restrict__ NEI,   // [N][256] bf16
    const unsigned short* __restrict__ Wt,    // [128][512] bf16
    float* __restrict__ out)
{
    __shared__ unsigned short As[128][72];   // 18432 B
    __shared__ unsigned short Bs[128][72];   // 18432 B

    const int tid  = threadIdx.x;
    const int w    = tid >> 6;
    const int lane = tid & 63;
    const int m0   = blockIdx.x * 128;
    const int wm   = (w & 1) * 64;
    const int wn   = (w >> 1) * 64;
    const int lm   = lane & 15;
    const int lk   = (lane >> 4) * 8;

    floatx4 acc[4][4];
    #pragma unroll
    for (int i = 0; i < 4; ++i)
        #pragma unroll
        for (int j = 0; j < 4; ++j)
            acc[i][j] = (floatx4){0.f, 0.f, 0.f, 0.f};

    for (int cc = 0; cc < 8; ++cc) {
        const int kb = cc * 64;
        // ---- stage A tile: 128 rows x 64 bf16 cols = 1024 int4 slots, 4/thread ----
        #pragma unroll
        for (int i = 0; i < 4; ++i) {
            int sl  = tid + i * 256;
            int row = sl >> 3;
            int o8  = (sl & 7) * 8;
            int node = m0 + row;
            if (node >= N_NODES) node = N_NODES - 1;
            const unsigned short* src;
            if (cc < 2) {
                int gcol = kb + o8;                 // 0..127 -> fea1 via slices
                int s    = gcol >> 5;
                int off  = gcol & 31;
                src = Gs + (size_t)s * NSLICE_ELEMS + node * 32 + off;
            } else if (cc < 4) {
                src = F2 + node * DIM + (kb - 128) + o8;
            } else {
                src = NEI + node * 256 + (kb - 256) + o8;
            }
            *(int4*)&As[row][o8] = *(const int4*)src;
        }
        // ---- stage B tile: 128 out-cols x 64 k = 1024 int4 slots, 4/thread ----
        #pragma unroll
        for (int i = 0; i < 4; ++i) {
            int sl  = tid + i * 256;
            int row = sl >> 3;
            int o8  = (sl & 7) * 8;
            *(int4*)&Bs[row][o8] = *(const int4*)(Wt + row * 512 + kb + o8);
        }
        __syncthreads();

        #pragma unroll
        for (int ks = 0; ks < 64; ks += 32) {
            short8 af[4], bf_[4];
            #pragma unroll
            for (int im = 0; im < 4; ++im)
                af[im] = *(const short8*)&As[wm + im * 16 + lm][ks + lk];
            #pragma unroll
            for (int in = 0; in < 4; ++in)
                bf_[in] = *(const short8*)&Bs[wn + in * 16 + lm][ks + lk];
            #pragma unroll
            for (int im = 0; im < 4; ++im)
                #pragma unroll
                for (int in = 0; in < 4; ++in)
                    acc[im][in] = __builtin_amdgcn_mfma_f32_16x16x32_bf16(
                        af[im], bf_[in], acc[im][in], 0, 0, 0);
        }
        __syncthreads();
    }

    // epilogue (C/D: col=lane&15, row=(lane>>4)*4+reg) — layout verified round 4
    #pragma unroll
    for (int im = 0; im < 4; ++im) {
        int rbase = m0 + wm + im * 16 + (lane >> 4) * 4;
        #pragma unroll
        for (int in = 0; in < 4; ++in) {
            int col = wn + in * 16 + lm;
            #pragma unroll
            for (int r = 0; r < 4; ++r) {
                int node = rbase + r;
                if (node < N_NODES)
                    out[node * DOUT + col] = fast_tanh(acc[im][in][r]);
            }
        }
    }
}

// ---------------- fallback (ws too small): round-1 fused fp32 ----------------
#define MT      64
#define KC      64
#define AS_STRIDE 68

__global__ __launch_bounds__(256) void sage_fused_fb(
    const float* __restrict__ fea1, const float* __restrict__ fea2,
    const int* __restrict__ idx1, const int* __restrict__ idx2,
    const float* __restrict__ W, float* __restrict__ out)
{
    __shared__ float As[KC][AS_STRIDE];
    __shared__ int   idxs[MT][64];
    const int tid = threadIdx.x;
    const int n0  = blockIdx.x * MT;
    #pragma unroll
    for (int i = 0; i < 8; ++i) {
        int e = tid + i * 256, m = e >> 5, kk = e & 31;
        int node = n0 + m; if (node >= N_NODES) node = N_NODES - 1;
        idxs[m][kk]      = idx1[node * KNEI + kk];
        idxs[m][32 + kk] = idx2[node * KNEI + kk];
    }
    float acc[8][4];
    #pragma unroll
    for (int i = 0; i < 8; ++i)
        #pragma unroll
        for (int j = 0; j < 4; ++j) acc[i][j] = 0.f;
    const int j0 = (tid & 31) * 4;
    const int m0 = (tid >> 5) * 8;
    for (int c = 0; c < 8; ++c) {
        if (c < 4) {
            const float* src = (c < 2) ? fea1 : fea2;
            const int cbase = (c & 1) * 64;
            #pragma unroll
            for (int i = 0; i < 4; ++i) {
                int f = tid + i * 256, m = f >> 4, c4 = (f & 15) * 4;
                int node = n0 + m; if (node >= N_NODES) node = N_NODES - 1;
                float4 v = *(const float4*)(src + node * DIM + cbase + c4);
                As[c4 + 0][m] = v.x; As[c4 + 1][m] = v.y;
                As[c4 + 2][m] = v.z; As[c4 + 3][m] = v.w;
            }
        } else {
            const int col = tid & 63, kbase = (c & 1) * 64;
            const int lbase = (c < 6) ? 0 : 32, g = tid >> 6;
            for (int mm = 0; mm < 16; ++mm) {
                const int m = g * 16 + mm;
                const int4* ip = (const int4*)&idxs[m][lbase];
                float s = 0.f;
                #pragma unroll
                for (int q = 0; q < 8; ++q) {
                    int4 nb = ip[q];
                    s += fea1[nb.x * DIM + kbase + col];
                    s += fea1[nb.y * DIM + kbase + col];
                    s += fea1[nb.z * DIM + kbase + col];
                    s += fea1[nb.w * DIM + kbase + col];
                }
                As[col][m] = s * (1.0f / 32.0f);
            }
        }
        __syncthreads();
        const float* wp = W + (c * KC) * DOUT + j0;
        #pragma unroll 4
        for (int k = 0; k < KC; ++k) {
            float4 w4 = *(const float4*)(wp + k * DOUT);
            const float4* ap = (const float4*)&As[k][m0];
            float4 a0 = ap[0]; float4 a1 = ap[1];
            float av[8] = {a0.x, a0.y, a0.z, a0.w, a1.x, a1.y, a1.z, a1.w};
            #pragma unroll
            for (int i = 0; i < 8; ++i) {
                acc[i][0] += av[i] * w4.x; acc[i][1] += av[i] * w4.y;
                acc[i][2] += av[i] * w4.z; acc[i][3] += av[i] * w4.w;
            }
        }
        __syncthreads();
    }
    #pragma unroll
    for (int i = 0; i < 8; ++i) {
        int node = n0 + m0 + i;
        if (node < N_NODES) {
            float4 r;
            r.x = tanhf(acc[i][0]); r.y = tanhf(acc[i][1]);
            r.z = tanhf(acc[i][2]); r.w = tanhf(acc[i][3]);
            *(float4*)(out + node * DOUT + j0) = r;
        }
    }
}

extern "C" void kernel_launch(void* const* d_in, const int* in_sizes, int n_in,
                              void* d_out, int out_size, void* d_ws, size_t ws_size,
                              hipStream_t stream) {
    const float* fea1 = (const float*)d_in[0];
    const float* fea2 = (const float*)d_in[1];
    const int*   idx1 = (const int*)d_in[2];
    const int*   idx2 = (const int*)d_in[3];
    const float* W    = (const float*)d_in[4];
    float* out = (float*)d_out;

    const size_t GS_BYTES  = (size_t)4 * NSLICE_ELEMS * 2;     // 12,800,000
    const size_t F2_BYTES  = (size_t)N_NODES * DIM * 2;        // 12,800,000
    const size_t NEI_BYTES = (size_t)N_NODES * 256 * 2;        // 25,600,000
    const size_t WT_BYTES  = (size_t)512 * 128 * 2;            // 131,072

    if (ws_size >= GS_BYTES + F2_BYTES + NEI_BYTES + WT_BYTES) {
        unsigned short* Gs  = (unsigned short*)d_ws;
        unsigned short* F2  = (unsigned short*)((char*)d_ws + GS_BYTES);
        unsigned short* NEI = (unsigned short*)((char*)d_ws + GS_BYTES + F2_BYTES);
        unsigned short* Wt  = (unsigned short*)((char*)d_ws + GS_BYTES + F2_BYTES + NEI_BYTES);

        convert2<<<2 * N_NODES * 16 / 256, 256, 0, stream>>>(fea1, fea2, Gs, F2);
        transpose_w<<<512 * 128 / 256, 256, 0, stream>>>(W, Wt);
        aggregate3<<<4 * NBLK, 256, 0, stream>>>(Gs, idx1, idx2, NEI);
        gemm128<<<(N_NODES + 127) / 128, 256, 0, stream>>>(Gs, F2, NEI, Wt, out);
    } else {
        const int grid = (N_NODES + MT - 1) / MT;
        sage_fused_fb<<<grid, 256, 0, stream>>>(fea1, fea2, idx1, idx2, W, out);
    }
}

// Round 9
// 167.677 us; speedup vs baseline: 1.2729x; 1.1657x over previous
//
#include <hip/hip_runtime.h>
#include <math.h>

#define N_NODES 50000
#define KNEI    32
#define DIM     128
#define DOUT    128
#define NUNITS  (2 * N_NODES)          // (node,list) units

typedef __attribute__((ext_vector_type(8))) short short8;
typedef __attribute__((ext_vector_type(4))) float floatx4;

// round-to-nearest-even fp32 -> bf16
static __device__ __forceinline__ unsigned short f2bf(float f) {
    unsigned int u = __float_as_uint(f);
    unsigned int lsb = (u >> 16) & 1u;
    u += 0x7fffu + lsb;
    return (unsigned short)(u >> 16);
}
static __device__ __forceinline__ unsigned int pack2(float a, float b) {
    return (unsigned int)f2bf(a) | ((unsigned int)f2bf(b) << 16);
}
// overflow-safe fast tanh: 1 - 2/(e^{2|x|}+1), sign-restored
static __device__ __forceinline__ float fast_tanh(float x) {
    float ax = fabsf(x);
    float e  = __expf(2.0f * ax);
    float t  = 1.0f - 2.0f / (e + 1.0f);
    return copysignf(t, x);
}
static __device__ __forceinline__ unsigned int pk4_i8(float a, float b, float c,
                                                      float d, float inv) {
    int qa = (int)rintf(a * inv) & 0xff;
    int qb = (int)rintf(b * inv) & 0xff;
    int qc = (int)rintf(c * inv) & 0xff;
    int qd = (int)rintf(d * inv) & 0xff;
    return (unsigned int)(qa | (qb << 8) | (qc << 16) | (qd << 24));
}

// ---------------- fast path kernels ----------------

// fea1 fp32 [N,128] -> int8 Q8[N][128] + per-node scale Sc[N]; 8 threads/node
__global__ __launch_bounds__(256) void convert_i8(
    const float* __restrict__ src, unsigned int* __restrict__ Q8,
    float* __restrict__ Sc)
{
    int t = blockIdx.x * 256 + threadIdx.x;   // 0 .. N*8-1
    if (t >= N_NODES * 8) return;
    int node = t >> 3, j = t & 7;
    const float* rp = src + node * DIM + j * 16;
    float4 v0 = *(const float4*)rp;
    float4 v1 = *(const float4*)(rp + 4);
    float4 v2 = *(const float4*)(rp + 8);
    float4 v3 = *(const float4*)(rp + 12);

    float am = fabsf(v0.x);
    am = fmaxf(am, fabsf(v0.y)); am = fmaxf(am, fabsf(v0.z)); am = fmaxf(am, fabsf(v0.w));
    am = fmaxf(am, fabsf(v1.x)); am = fmaxf(am, fabsf(v1.y));
    am = fmaxf(am, fabsf(v1.z)); am = fmaxf(am, fabsf(v1.w));
    am = fmaxf(am, fabsf(v2.x)); am = fmaxf(am, fabsf(v2.y));
    am = fmaxf(am, fabsf(v2.z)); am = fmaxf(am, fabsf(v2.w));
    am = fmaxf(am, fabsf(v3.x)); am = fmaxf(am, fabsf(v3.y));
    am = fmaxf(am, fabsf(v3.z)); am = fmaxf(am, fabsf(v3.w));
    // reduce absmax across the node's 8 threads (aligned group within a wave)
    #pragma unroll
    for (int d = 1; d < 8; d <<= 1) am = fmaxf(am, __shfl_xor(am, d, 64));

    float inv = (am > 1e-30f) ? 127.0f / am : 0.0f;
    int4 o;
    o.x = (int)pk4_i8(v0.x, v0.y, v0.z, v0.w, inv);
    o.y = (int)pk4_i8(v1.x, v1.y, v1.z, v1.w, inv);
    o.z = (int)pk4_i8(v2.x, v2.y, v2.z, v2.w, inv);
    o.w = (int)pk4_i8(v3.x, v3.y, v3.z, v3.w, inv);
    *(int4*)(Q8 + node * 32 + j * 4) = o;
    if (j == 0) Sc[node] = am * (1.0f / 127.0f);
}

// W fp32 [512,128] -> Wt bf16 [128][512]
__global__ __launch_bounds__(256) void transpose_w(
    const float* __restrict__ W, unsigned short* __restrict__ Wt)
{
    int t = blockIdx.x * 256 + threadIdx.x;   // 0..65535
    int k = t >> 7, n = t & 127;
    Wt[n * 512 + k] = f2bf(W[t]);
}

// gather-mean over int8 table with per-row scale. 8 lanes/unit (16B chunk of
// the 128B row), 32 units per 256-thread block; indices+scales staged in LDS.
__global__ __launch_bounds__(256) void aggregate_i8(
    const unsigned char* __restrict__ Q8,
    const float* __restrict__ Sc,
    const int* __restrict__ idx1,
    const int* __restrict__ idx2,
    unsigned short* __restrict__ NEI)
{
    __shared__ int   idxs[32][32];   // [unit-in-block][neighbor]
    __shared__ float scs[32][32];

    const int tid = threadIdx.x;
    const int bu0 = blockIdx.x * 32;            // first unit of block
    const int ul  = tid >> 3;                   // unit-in-block 0..31
    const int l   = tid & 7;                    // 16B chunk / scale quarter

    // ---- stage indices: 32 units x 32 ints, 1 int4/thread ----
    {
        int uu = bu0 + ul;                      // 3125*32 == NUNITS exactly
        const int* ip = ((uu & 1) ? idx2 : idx1) + (uu >> 1) * KNEI + l * 4;
        int4 v = *(const int4*)ip;
        *(int4*)&idxs[ul][l * 4] = v;
    }
    __syncthreads();

    // ---- stage scales: lane l gathers 4 of its unit's 32 ----
    {
        #pragma unroll
        for (int k = 0; k < 4; ++k)
            scs[ul][l * 4 + k] = Sc[idxs[ul][l * 4 + k]];
    }
    __syncthreads();

    const int u    = bu0 + ul;
    const int node = u >> 1;
    const int list = u & 1;

    // pull this unit's 32 indices into registers (LDS broadcast across 8 lanes)
    int4 I[8];
    #pragma unroll
    for (int q = 0; q < 8; ++q) I[q] = *(const int4*)&idxs[ul][q * 4];

    const unsigned char* base = Q8 + l * 16;
    float sums[16];
    #pragma unroll
    for (int i = 0; i < 16; ++i) sums[i] = 0.f;

    #pragma unroll
    for (int q = 0; q < 8; ++q) {
        int rows[4] = {I[q].x, I[q].y, I[q].z, I[q].w};
        #pragma unroll
        for (int t4 = 0; t4 < 4; ++t4) {
            int4 v = *(const int4*)(base + (size_t)rows[t4] * 128);
            float s = scs[ul][q * 4 + t4];
            int d[4] = {v.x, v.y, v.z, v.w};
            #pragma unroll
            for (int j = 0; j < 4; ++j) {
                int w = d[j];
                sums[4 * j + 0] = fmaf(s, (float)((w << 24) >> 24), sums[4 * j + 0]);
                sums[4 * j + 1] = fmaf(s, (float)((w << 16) >> 24), sums[4 * j + 1]);
                sums[4 * j + 2] = fmaf(s, (float)((w <<  8) >> 24), sums[4 * j + 2]);
                sums[4 * j + 3] = fmaf(s, (float)( w        >> 24), sums[4 * j + 3]);
            }
        }
    }

    const float invK = 1.0f / 32.0f;
    int4 o0, o1;
    o0.x = (int)pack2(sums[0] * invK,  sums[1] * invK);
    o0.y = (int)pack2(sums[2] * invK,  sums[3] * invK);
    o0.z = (int)pack2(sums[4] * invK,  sums[5] * invK);
    o0.w = (int)pack2(sums[6] * invK,  sums[7] * invK);
    o1.x = (int)pack2(sums[8] * invK,  sums[9] * invK);
    o1.y = (int)pack2(sums[10] * invK, sums[11] * invK);
    o1.z = (int)pack2(sums[12] * invK, sums[13] * invK);
    o1.w = (int)pack2(sums[14] * invK, sums[15] * invK);
    unsigned short* op = NEI + node * 256 + list * 128 + l * 16;
    *(int4*)op       = o0;
    *(int4*)(op + 8) = o1;
}

// out = tanh([fea1|fea2|nei1|nei2] @ Wt^T); 128x128 tile, bf16 MFMA, fp32 accum.
// fea1/fea2 staged from fp32 with inline bf16 conversion (full precision path).
__global__ __launch_bounds__(256) void gemm128(
    const float*          __restrict__ fea1,
    const float*          __restrict__ fea2,
    const unsigned short* __restrict__ NEI,   // [N][256] bf16
    const unsigned short* __restrict__ Wt,    // [128][512] bf16
    float* __restrict__ out)
{
    __shared__ unsigned short As[128][72];   // 18432 B
    __shared__ unsigned short Bs[128][72];   // 18432 B

    const int tid  = threadIdx.x;
    const int w    = tid >> 6;
    const int lane = tid & 63;
    const int m0   = blockIdx.x * 128;
    const int wm   = (w & 1) * 64;
    const int wn   = (w >> 1) * 64;
    const int lm   = lane & 15;
    const int lk   = (lane >> 4) * 8;

    floatx4 acc[4][4];
    #pragma unroll
    for (int i = 0; i < 4; ++i)
        #pragma unroll
        for (int j = 0; j < 4; ++j)
            acc[i][j] = (floatx4){0.f, 0.f, 0.f, 0.f};

    for (int cc = 0; cc < 8; ++cc) {
        const int kb = cc * 64;
        // ---- stage A tile: 128 rows x 64 bf16 cols ----
        if (cc < 4) {
            const float* src = (cc < 2) ? fea1 : fea2;
            const int cbase = (cc & 1) * 64;
            #pragma unroll
            for (int i = 0; i < 8; ++i) {
                int f   = tid + i * 256;      // 0..2047 float4 slots
                int row = f >> 4;             // 16 float4 per 64-col chunk
                int c4  = (f & 15) * 4;
                int node = m0 + row;
                if (node >= N_NODES) node = N_NODES - 1;
                float4 v = *(const float4*)(src + node * DIM + cbase + c4);
                *(unsigned int*)&As[row][c4 + 0] = pack2(v.x, v.y);
                *(unsigned int*)&As[row][c4 + 2] = pack2(v.z, v.w);
            }
        } else {
            const int cb = kb - 256;
            #pragma unroll
            for (int i = 0; i < 4; ++i) {
                int sl  = tid + i * 256;      // 1024 int4 slots
                int row = sl >> 3;
                int o8  = (sl & 7) * 8;
                int node = m0 + row;
                if (node >= N_NODES) node = N_NODES - 1;
                *(int4*)&As[row][o8] = *(const int4*)(NEI + node * 256 + cb + o8);
            }
        }
        // ---- stage B tile: 128 out-cols x 64 k ----
        #pragma unroll
        for (int i = 0; i < 4; ++i) {
            int sl  = tid + i * 256;
            int row = sl >> 3;
            int o8  = (sl & 7) * 8;
            *(int4*)&Bs[row][o8] = *(const int4*)(Wt + row * 512 + kb + o8);
        }
        __syncthreads();

        #pragma unroll
        for (int ks = 0; ks < 64; ks += 32) {
            short8 af[4], bf_[4];
            #pragma unroll
            for (int im = 0; im < 4; ++im)
                af[im] = *(const short8*)&As[wm + im * 16 + lm][ks + lk];
            #pragma unroll
            for (int in = 0; in < 4; ++in)
                bf_[in] = *(const short8*)&Bs[wn + in * 16 + lm][ks + lk];
            #pragma unroll
            for (int im = 0; im < 4; ++im)
                #pragma unroll
                for (int in = 0; in < 4; ++in)
                    acc[im][in] = __builtin_amdgcn_mfma_f32_16x16x32_bf16(
                        af[im], bf_[in], acc[im][in], 0, 0, 0);
        }
        __syncthreads();
    }

    // epilogue (C/D: col=lane&15, row=(lane>>4)*4+reg) — layout verified round 4
    #pragma unroll
    for (int im = 0; im < 4; ++im) {
        int rbase = m0 + wm + im * 16 + (lane >> 4) * 4;
        #pragma unroll
        for (int in = 0; in < 4; ++in) {
            int col = wn + in * 16 + lm;
            #pragma unroll
            for (int r = 0; r < 4; ++r) {
                int node = rbase + r;
                if (node < N_NODES)
                    out[node * DOUT + col] = fast_tanh(acc[im][in][r]);
            }
        }
    }
}

// ---------------- fallback (ws too small): round-1 fused fp32 ----------------
#define MT      64
#define KC      64
#define AS_STRIDE 68

__global__ __launch_bounds__(256) void sage_fused_fb(
    const float* __restrict__ fea1, const float* __restrict__ fea2,
    const int* __restrict__ idx1, const int* __restrict__ idx2,
    const float* __restrict__ W, float* __restrict__ out)
{
    __shared__ float As[KC][AS_STRIDE];
    __shared__ int   idxs[MT][64];
    const int tid = threadIdx.x;
    const int n0  = blockIdx.x * MT;
    #pragma unroll
    for (int i = 0; i < 8; ++i) {
        int e = tid + i * 256, m = e >> 5, kk = e & 31;
        int node = n0 + m; if (node >= N_NODES) node = N_NODES - 1;
        idxs[m][kk]      = idx1[node * KNEI + kk];
        idxs[m][32 + kk] = idx2[node * KNEI + kk];
    }
    float acc[8][4];
    #pragma unroll
    for (int i = 0; i < 8; ++i)
        #pragma unroll
        for (int j = 0; j < 4; ++j) acc[i][j] = 0.f;
    const int j0 = (tid & 31) * 4;
    const int m0 = (tid >> 5) * 8;
    for (int c = 0; c < 8; ++c) {
        if (c < 4) {
            const float* src = (c < 2) ? fea1 : fea2;
            const int cbase = (c & 1) * 64;
            #pragma unroll
            for (int i = 0; i < 4; ++i) {
                int f = tid + i * 256, m = f >> 4, c4 = (f & 15) * 4;
                int node = n0 + m; if (node >= N_NODES) node = N_NODES - 1;
                float4 v = *(const float4*)(src + node * DIM + cbase + c4);
                As[c4 + 0][m] = v.x; As[c4 + 1][m] = v.y;
                As[c4 + 2][m] = v.z; As[c4 + 3][m] = v.w;
            }
        } else {
            const int col = tid & 63, kbase = (c & 1) * 64;
            const int lbase = (c < 6) ? 0 : 32, g = tid >> 6;
            for (int mm = 0; mm < 16; ++mm) {
                const int m = g * 16 + mm;
                const int4* ip = (const int4*)&idxs[m][lbase];
                float s = 0.f;
                #pragma unroll
                for (int q = 0; q < 8; ++q) {
                    int4 nb = ip[q];
                    s += fea1[nb.x * DIM + kbase + col];
                    s += fea1[nb.y * DIM + kbase + col];
                    s += fea1[nb.z * DIM + kbase + col];
                    s += fea1[nb.w * DIM + kbase + col];
                }
                As[col][m] = s * (1.0f / 32.0f);
            }
        }
        __syncthreads();
        const float* wp = W + (c * KC) * DOUT + j0;
        #pragma unroll 4
        for (int k = 0; k < KC; ++k) {
            float4 w4 = *(const float4*)(wp + k * DOUT);
            const float4* ap = (const float4*)&As[k][m0];
            float4 a0 = ap[0]; float4 a1 = ap[1];
            float av[8] = {a0.x, a0.y, a0.z, a0.w, a1.x, a1.y, a1.z, a1.w};
            #pragma unroll
            for (int i = 0; i < 8; ++i) {
                acc[i][0] += av[i] * w4.x; acc[i][1] += av[i] * w4.y;
                acc[i][2] += av[i] * w4.z; acc[i][3] += av[i] * w4.w;
            }
        }
        __syncthreads();
    }
    #pragma unroll
    for (int i = 0; i < 8; ++i) {
        int node = n0 + m0 + i;
        if (node < N_NODES) {
            float4 r;
            r.x = tanhf(acc[i][0]); r.y = tanhf(acc[i][1]);
            r.z = tanhf(acc[i][2]); r.w = tanhf(acc[i][3]);
            *(float4*)(out + node * DOUT + j0) = r;
        }
    }
}

extern "C" void kernel_launch(void* const* d_in, const int* in_sizes, int n_in,
                              void* d_out, int out_size, void* d_ws, size_t ws_size,
                              hipStream_t stream) {
    const float* fea1 = (const float*)d_in[0];
    const float* fea2 = (const float*)d_in[1];
    const int*   idx1 = (const int*)d_in[2];
    const int*   idx2 = (const int*)d_in[3];
    const float* W    = (const float*)d_in[4];
    float* out = (float*)d_out;

    const size_t Q8_BYTES  = (size_t)N_NODES * DIM;            //  6,400,000
    const size_t SC_BYTES  = (size_t)N_NODES * 4;              //    200,000
    const size_t NEI_BYTES = (size_t)N_NODES * 256 * 2;        // 25,600,000
    const size_t WT_BYTES  = (size_t)512 * 128 * 2;            //    131,072

    if (ws_size >= Q8_BYTES + SC_BYTES + NEI_BYTES + WT_BYTES) {
        unsigned char*  Q8  = (unsigned char*)d_ws;
        float*          Scp = (float*)((char*)d_ws + Q8_BYTES);
        unsigned short* NEI = (unsigned short*)((char*)d_ws + Q8_BYTES + SC_BYTES);
        unsigned short* Wt  = (unsigned short*)((char*)d_ws + Q8_BYTES + SC_BYTES + NEI_BYTES);

        convert_i8<<<(N_NODES * 8 + 255) / 256, 256, 0, stream>>>(
            fea1, (unsigned int*)Q8, Scp);
        transpose_w<<<512 * 128 / 256, 256, 0, stream>>>(W, Wt);
        aggregate_i8<<<NUNITS / 32, 256, 0, stream>>>(Q8, Scp, idx1, idx2, NEI);
        gemm128<<<(N_NODES + 127) / 128, 256, 0, stream>>>(fea1, fea2, NEI, Wt, out);
    } else {
        const int grid = (N_NODES + MT - 1) / MT;
        sage_fused_fb<<<grid, 256, 0, stream>>>(fea1, fea2, idx1, idx2, W, out);
    }
}